// Round 13
// baseline (333.843 us; speedup 1.0000x reference)
//
#include <hip/hip_runtime.h>
#include <hip/hip_bf16.h>

// h stored bf16 chunk layout [b][4][65536 px][16c] (entry = 32 B)
// k_offconv: implicit-GEMM MFMA 16x16x32 bf16, batched A-loads (18 in flight),
//            grid 1024 (4 blk/CU), 2 tiles/wave
// k_dsc: GN+tanh inline, 2-pt lerp (bf16 h -> fp32) + K=5 conv -> cat
// final: GN + 1x1 conv 16->64 + BN + ReLU -> fp32 NCHW

#define EPSF 1e-5f

typedef __attribute__((ext_vector_type(4))) float f4;
typedef __attribute__((ext_vector_type(8))) short bf8;
typedef __attribute__((ext_vector_type(8))) unsigned short us8;

static __device__ __forceinline__ unsigned pk2(float lo, float hi) {
    unsigned a = __float_as_uint(lo), b = __float_as_uint(hi);
    a = (a + 0x7FFFu + ((a >> 16) & 1)) >> 16;
    b = (b + 0x7FFFu + ((b >> 16) & 1)) >> 16;
    return a | (b << 16);
}
static __device__ __forceinline__ float bu2f(unsigned short u) {
    return __uint_as_float(((unsigned)u) << 16);
}

// ---------------- Kernel 1: conv1 + bn1 + relu -> h bf16 chunked --------------
__global__ __launch_bounds__(256) void k_conv1(
    const float* __restrict__ x, const float* __restrict__ w,
    const float* __restrict__ g, const float* __restrict__ bb,
    const float* __restrict__ m, const float* __restrict__ v,
    unsigned short* __restrict__ hb, float* __restrict__ statsraw)
{
    __shared__ float wl[27 * 64];            // [tap][oc]
    __shared__ float scale[64], shift[64];
    int t = threadIdx.x;
    if (blockIdx.x == 0 && t < 64) statsraw[t] = 0.f;   // zero raw(40)+raw2(16)
    for (int idx = t; idx < 1728; idx += 256) {
        int tap = idx >> 6, oc = idx & 63;
        wl[idx] = w[oc * 27 + tap];
    }
    if (t < 64) {
        float sc = g[t] * rsqrtf(v[t] + EPSF);
        scale[t] = sc; shift[t] = bb[t] - m[t] * sc;
    }
    __syncthreads();
    int lane = t & 63, wid = t >> 6;
    int blk = blockIdx.x;
    int b = blk >> 9;
    int rem = blk & 511;
    int i0 = (rem >> 2) * 2;
    int j0 = (rem & 3) * 64;
    int j = j0 + lane;
    f4 acc[2][4];
    #pragma unroll
    for (int r = 0; r < 2; ++r)
        #pragma unroll
        for (int q = 0; q < 4; ++q) acc[r][q] = (f4)0.f;
    #pragma unroll
    for (int ic = 0; ic < 3; ++ic) {
        #pragma unroll
        for (int dy = 0; dy < 3; ++dy) {
            const float* rowp[2]; bool vy[2];
            #pragma unroll
            for (int r = 0; r < 2; ++r) {
                int y = 2 * (i0 + r) + dy - 1;
                vy[r] = (unsigned)y < 512u;
                rowp[r] = x + ((size_t)(b * 3 + ic) * 512 + (vy[r] ? y : 0)) * 512;
            }
            #pragma unroll
            for (int dx = 0; dx < 3; ++dx) {
                int xx = 2 * j + dx - 1;
                bool vx = (unsigned)xx < 512u;
                int tap = ic * 9 + dy * 3 + dx;
                f4 w4[4];
                #pragma unroll
                for (int q = 0; q < 4; ++q)
                    w4[q] = *(const f4*)&wl[tap * 64 + wid * 16 + q * 4];
                #pragma unroll
                for (int r = 0; r < 2; ++r) {
                    float xv = (vy[r] && vx) ? rowp[r][xx] : 0.f;
                    #pragma unroll
                    for (int q = 0; q < 4; ++q) acc[r][q] += xv * w4[q];
                }
            }
        }
    }
    #pragma unroll
    for (int r = 0; r < 2; ++r) {
        size_t ij = (size_t)(i0 + r) * 256 + j;
        unsigned* hp = (unsigned*)(hb + ((size_t)(b * 4 + wid) * 65536 + ij) * 16);
        unsigned u[8];
        #pragma unroll
        for (int q = 0; q < 4; ++q) {
            f4 sc = *(const f4*)&scale[wid * 16 + q * 4];
            f4 sh = *(const f4*)&shift[wid * 16 + q * 4];
            f4 val = acc[r][q] * sc + sh;
            float v0 = fmaxf(val[0], 0.f), v1 = fmaxf(val[1], 0.f);
            float v2 = fmaxf(val[2], 0.f), v3 = fmaxf(val[3], 0.f);
            u[q * 2] = pk2(v0, v1);
            u[q * 2 + 1] = pk2(v2, v3);
        }
        *(uint4*)hp = make_uint4(u[0], u[1], u[2], u[3]);
        *(uint4*)(hp + 4) = make_uint4(u[4], u[5], u[6], u[7]);
    }
}

// ---------------- Kernel 2: offset convs via MFMA implicit GEMM ---------------
// grid 1024 x 256 thr (4 waves, 4 blk/CU); wave does 2 tiles of 16 px; N=32.
// A-loads for all 18 (tap,kt) batched in registers before the MFMA loop.
__global__ __launch_bounds__(256) void k_offconv(
    const unsigned short* __restrict__ hb,
    const float* __restrict__ wx, const float* __restrict__ wy,
    const float* __restrict__ bx, const float* __restrict__ by,
    float* __restrict__ offx, float* __restrict__ offy,
    float* __restrict__ raw)
{
    __shared__ short bstage[18432];          // [tap][kt][nt][lane][8] bf16, 36 KB
    __shared__ float wsum[4][2][16][2];
    int t = threadIdx.x;
    for (int idx = t; idx < 18432; idx += 256) {
        int jj = idx & 7;
        int lane_ = (idx >> 3) & 63;
        int nt = (idx >> 9) & 1;
        int kt = (idx >> 10) & 1;
        int tap = idx >> 11;
        int c = kt * 32 + (lane_ >> 4) * 8 + jj;
        int oc = nt * 16 + (lane_ & 15);
        float v = 0.f;
        if (oc < 10) v = wx[((size_t)oc * 64 + c) * 9 + tap];
        else if (oc < 20) v = wy[((size_t)(oc - 10) * 64 + c) * 9 + tap];
        unsigned uu = __float_as_uint(v);
        uu = (uu + 0x7FFFu + ((uu >> 16) & 1)) >> 16;
        bstage[idx] = (short)uu;
    }
    __syncthreads();
    int lane = t & 63, wid = t >> 6;
    int m = lane & 15, quad = lane >> 4;
    int blk = blockIdx.x;
    int b = blk >> 9;
    float bias_a = (m < 10) ? bx[m] : by[m - 10];
    bool vb = (m < 4);
    float bias_b = vb ? by[6 + m] : 0.f;
    float s0 = 0.f, q0 = 0.f, s1 = 0.f, q1 = 0.f;
    const unsigned short* hb_b = hb + (size_t)b * 4194304;
    #pragma unroll 1
    for (int tt = 0; tt < 2; ++tt) {
        int p0 = blk * 128 + wid * 32 + tt * 16;
        int ij = p0 & 65535;
        int i = ij >> 8, j0 = ij & 255;
        // ---- batch all 18 A-fragment loads ----
        bf8 afr[18];
        #pragma unroll
        for (int ky = 0; ky < 3; ++ky) {
            int y = i + ky - 1;
            bool vy = (unsigned)y < 256u;
            int yc = vy ? y : 0;
            #pragma unroll
            for (int kx = 0; kx < 3; ++kx) {
                int xc = j0 + m + kx - 1;
                bool vx = (unsigned)xc < 256u;
                bool ok = vy && vx;
                int pix = yc * 256 + (vx ? xc : 0);
                #pragma unroll
                for (int kt = 0; kt < 2; ++kt) {
                    int chunkk = kt * 2 + (quad >> 1);
                    const unsigned short* ap =
                        hb_b + ((size_t)chunkk * 65536 + pix) * 16 + (quad & 1) * 8;
                    bf8 av = *(const bf8*)ap;
                    afr[(ky * 3 + kx) * 2 + kt] = ok ? av : (bf8)0;
                }
            }
        }
        // ---- MFMA over all 18 K-slices ----
        f4 acc0 = (f4)0.f, acc1 = (f4)0.f;
        #pragma unroll
        for (int e = 0; e < 18; ++e) {
            const short* bp = &bstage[(size_t)e * 1024 + lane * 8];
            bf8 b0 = *(const bf8*)bp;
            bf8 b1 = *(const bf8*)(bp + 512);
            acc0 = __builtin_amdgcn_mfma_f32_16x16x32_bf16(afr[e], b0, acc0, 0, 0, 0);
            acc1 = __builtin_amdgcn_mfma_f32_16x16x32_bf16(afr[e], b1, acc1, 0, 0, 0);
        }
        // ---- epilogue: bias, store, stats partials ----
        #pragma unroll
        for (int r = 0; r < 4; ++r) {
            int p = p0 + quad * 4 + r;
            float v0 = acc0[r] + bias_a;
            s0 += v0; q0 += v0 * v0;
            if (m < 10) offx[(size_t)p * 10 + m] = v0;
            else        offy[(size_t)p * 10 + m - 10] = v0;
            if (vb) {
                float v1 = acc1[r] + bias_b;
                s1 += v1; q1 += v1 * v1;
                offy[(size_t)p * 10 + 6 + m] = v1;
            }
        }
    }
    s0 += __shfl_xor(s0, 16, 64); q0 += __shfl_xor(q0, 16, 64);
    s1 += __shfl_xor(s1, 16, 64); q1 += __shfl_xor(q1, 16, 64);
    s0 += __shfl_xor(s0, 32, 64); q0 += __shfl_xor(q0, 32, 64);
    s1 += __shfl_xor(s1, 32, 64); q1 += __shfl_xor(q1, 32, 64);
    if (quad == 0) {
        wsum[wid][0][m][0] = s0; wsum[wid][0][m][1] = q0;
        wsum[wid][1][m][0] = s1; wsum[wid][1][m][1] = q1;
    }
    __syncthreads();
    if (t < 20) {
        float ss = 0.f, qq = 0.f;
        if (t < 16) {
            #pragma unroll
            for (int w_ = 0; w_ < 4; ++w_) { ss += wsum[w_][0][t][0]; qq += wsum[w_][0][t][1]; }
        } else {
            #pragma unroll
            for (int w_ = 0; w_ < 4; ++w_) { ss += wsum[w_][1][t - 16][0]; qq += wsum[w_][1][t - 16][1]; }
        }
        int oc = t;
        int branch = oc < 10 ? 0 : 1;
        int c = oc - branch * 10;
        int gid = branch * 10 + b * 5 + (c >> 1);
        atomicAdd(&raw[gid * 2], ss);
        atomicAdd(&raw[gid * 2 + 1], qq);
    }
}

// ---------------- Kernel 3: GN+tanh inline + 2pt-lerp (bf16) + deform conv ----
// block = 256; 64 j (lanes) x 4 i (4 waves x 1 row). grid (512,2).
__global__ __launch_bounds__(256) void k_dsc(
    const unsigned short* __restrict__ hb,
    const float* __restrict__ offx, const float* __restrict__ offy,
    const float* __restrict__ raw,
    const float* __restrict__ gx, const float* __restrict__ bxg,
    const float* __restrict__ gy, const float* __restrict__ byg,
    const float* __restrict__ wx_, const float* __restrict__ wy_,
    const float* __restrict__ bx_, const float* __restrict__ by_,
    float* __restrict__ cat,
    float* __restrict__ raw2)
{
    int branch = blockIdx.y;
    __shared__ float wl[2560];               // [k][c][oc8]
    __shared__ float bias[8];
    __shared__ float ws2[4][4];
    const float* wsrc = branch ? wy_ : wx_;
    int t = threadIdx.x;
    for (int idx = t; idx < 2560; idx += 256) {
        int oc = idx & 7;
        int rest = idx >> 3;                 // k*64 + c
        wl[idx] = wsrc[(size_t)oc * 320 + (rest & 63) * 5 + (rest >> 6)];
    }
    if (t < 8) bias[t] = (branch ? by_ : bx_)[t];
    __syncthreads();
    int lane = t & 63, wid = t >> 6;
    int blk = blockIdx.x;
    int b = blk >> 8;
    int rem = blk & 255;
    int i = (rem >> 2) * 4 + wid;
    int j = (rem & 3) * 64 + lane;
    const float* offarr = branch ? offy : offx;
    const float* goff = branch ? gy : gx;
    const float* boff = branch ? byg : bxg;
    int cbase = branch * 5;
    const int idxs[4] = {0, 1, 3, 4};
    float cum[5];
    {
        size_t p = (size_t)b * 65536 + (size_t)i * 256 + j;
        const float* op = offarr + p * 10 + cbase;
        float tv[4];
        #pragma unroll
        for (int u = 0; u < 4; ++u) {
            int c = cbase + idxs[u];
            int g = c >> 1;
            int sidx = branch * 10 + b * 5 + g;
            float ss = raw[sidx * 2], qq = raw[sidx * 2 + 1];
            float mean = ss * (1.f / 131072.f);
            float var = qq * (1.f / 131072.f) - mean * mean;
            float val = (op[idxs[u]] - mean) * rsqrtf(var + EPSF) * goff[c] + boff[c];
            tv[u] = tanhf(val);
        }
        cum[0] = tv[0] + tv[1]; cum[1] = tv[1]; cum[2] = 0.f;
        cum[3] = tv[2]; cum[4] = tv[2] + tv[3];
    }
    f4 acc0 = (f4)0.f, acc1 = (f4)0.f;
    #pragma unroll 1
    for (int k = 0; k < 5; ++k) {
        int pixA, pixB; float fr;
        if (branch == 0) {
            float yf = (float)i + cum[k];
            yf = fminf(fmaxf(yf, 0.f), 255.f);
            float y0 = floorf(yf);
            fr = yf - y0;
            int y0i = (int)y0;
            int y1i = min(y0i + 1, 255);
            int xi = min(max(j + k - 2, 0), 255);
            pixA = y0i * 256 + xi;
            pixB = y1i * 256 + xi;
        } else {
            float xf = (float)j + cum[k];
            xf = fminf(fmaxf(xf, 0.f), 255.f);
            float x0 = floorf(xf);
            fr = xf - x0;
            int x0i = (int)x0;
            int x1i = min(x0i + 1, 255);
            int yi = min(max(i + k - 2, 0), 255);
            pixA = yi * 256 + x0i;
            pixB = yi * 256 + x1i;
        }
        #pragma unroll 1
        for (int chunk = 0; chunk < 4; ++chunk) {
            const unsigned short* hc = hb + ((size_t)(b * 4 + chunk) * 65536) * 16;
            const float* wk = &wl[((size_t)k * 64 + chunk * 16) * 8];
            us8 aLo = *(const us8*)(hc + (size_t)pixA * 16);
            us8 aHi = *(const us8*)(hc + (size_t)pixA * 16 + 8);
            us8 bLo = *(const us8*)(hc + (size_t)pixB * 16);
            us8 bHi = *(const us8*)(hc + (size_t)pixB * 16 + 8);
            #pragma unroll
            for (int cq = 0; cq < 4; ++cq) {
                #pragma unroll
                for (int ci = 0; ci < 4; ++ci) {
                    int e = cq * 4 + ci;
                    float av = (e < 8) ? bu2f(aLo[e & 7]) : bu2f(aHi[e & 7]);
                    float bv = (e < 8) ? bu2f(bLo[e & 7]) : bu2f(bHi[e & 7]);
                    float vf = av + fr * (bv - av);
                    f4 w0 = *(const f4*)&wk[e * 8];
                    f4 w1 = *(const f4*)&wk[e * 8 + 4];
                    acc0 += vf * w0;
                    acc1 += vf * w1;
                }
            }
        }
    }
    float sg0 = 0.f, sq0 = 0.f, sg1 = 0.f, sq1 = 0.f;
    {
        size_t p = (size_t)b * 65536 + (size_t)i * 256 + j;
        f4 v0 = acc0 + *(const f4*)&bias[0];
        f4 v1 = acc1 + *(const f4*)&bias[4];
        *(f4*)&cat[p * 16 + branch * 8] = v0;
        *(f4*)&cat[p * 16 + branch * 8 + 4] = v1;
        #pragma unroll
        for (int e = 0; e < 4; ++e) {
            sg0 += v0[e]; sq0 += v0[e] * v0[e];
            sg1 += v1[e]; sq1 += v1[e] * v1[e];
        }
    }
    #pragma unroll
    for (int d = 32; d >= 1; d >>= 1) {
        sg0 += __shfl_xor(sg0, d, 64); sq0 += __shfl_xor(sq0, d, 64);
        sg1 += __shfl_xor(sg1, d, 64); sq1 += __shfl_xor(sq1, d, 64);
    }
    if (lane == 0) {
        ws2[wid][0] = sg0; ws2[wid][1] = sq0; ws2[wid][2] = sg1; ws2[wid][3] = sq1;
    }
    __syncthreads();
    if (t < 4) {
        float val = ws2[0][t] + ws2[1][t] + ws2[2][t] + ws2[3][t];
        int g0 = b * 4 + branch * 2;
        int gi = g0 + (t >> 1);
        atomicAdd(&raw2[gi * 2 + (t & 1)], val);
    }
}

// ---------------- Kernel 4: GN+relu + 1x1 conv + bn2 + relu -> fp32 out -------
__global__ __launch_bounds__(256) void k_final(
    const float* __restrict__ cat,
    const float* __restrict__ raw2,
    const float* __restrict__ gnx_g, const float* __restrict__ gnx_b,
    const float* __restrict__ gny_g, const float* __restrict__ gny_b,
    const float* __restrict__ w2,
    const float* __restrict__ g2, const float* __restrict__ b2,
    const float* __restrict__ m2, const float* __restrict__ v2,
    float* __restrict__ out)
{
    __shared__ float wl[1024];
    __shared__ float sc2[64], sh2[64];
    __shared__ float cmean[16], crstd[16], cg[16], cb[16];
    int t = threadIdx.x;
    int pbase = blockIdx.x * 64;
    int b = pbase >> 16;
    for (int idx = t; idx < 1024; idx += 256) wl[idx] = w2[idx];
    if (t < 64) {
        float sc = g2[t] * rsqrtf(v2[t] + EPSF);
        sc2[t] = sc;
        sh2[t] = b2[t] - m2[t] * sc;
    }
    if (t < 16) {
        int branch = t >> 3; int cc = t & 7; int g = cc >> 2;
        int sidx = b * 4 + branch * 2 + g;
        float ss = raw2[sidx * 2], qq = raw2[sidx * 2 + 1];
        float mean = ss * (1.f / 262144.f);
        float var = qq * (1.f / 262144.f) - mean * mean;
        cmean[t] = mean;
        crstd[t] = rsqrtf(var + EPSF);
        cg[t] = branch ? gny_g[cc] : gnx_g[cc];
        cb[t] = branch ? gny_b[cc] : gnx_b[cc];
    }
    __syncthreads();
    int lane = t & 63, wq = t >> 6;
    int p = pbase + lane;
    int ij = p & 65535;
    float vv[16];
    const float* cp = &cat[(size_t)p * 16];
    #pragma unroll
    for (int c = 0; c < 16; ++c) {
        float x = (cp[c] - cmean[c]) * crstd[c] * cg[c] + cb[c];
        vv[c] = fmaxf(x, 0.f);
    }
    #pragma unroll
    for (int q = 0; q < 16; ++q) {
        int oc = wq + q * 4;
        float s = 0.f;
        #pragma unroll
        for (int c = 0; c < 16; ++c) s += vv[c] * wl[oc * 16 + c];
        float r = fmaxf(s * sc2[oc] + sh2[oc], 0.f);
        out[((size_t)(b * 64 + oc) << 16) + ij] = r;
    }
}

extern "C" void kernel_launch(void* const* d_in, const int* in_sizes, int n_in,
                              void* d_out, int out_size, void* d_ws, size_t ws_size,
                              hipStream_t stream) {
    const float* x       = (const float*)d_in[0];
    const float* conv1_w = (const float*)d_in[1];
    const float* bn1_g   = (const float*)d_in[2];
    const float* bn1_b   = (const float*)d_in[3];
    const float* bn1_m   = (const float*)d_in[4];
    const float* bn1_v   = (const float*)d_in[5];
    const float* offx_w  = (const float*)d_in[6];
    const float* offx_b  = (const float*)d_in[7];
    const float* gnoffx_g= (const float*)d_in[8];
    const float* gnoffx_b= (const float*)d_in[9];
    const float* dscx_w  = (const float*)d_in[10];
    const float* dscx_b  = (const float*)d_in[11];
    const float* gnx_g   = (const float*)d_in[12];
    const float* gnx_b   = (const float*)d_in[13];
    const float* offy_w  = (const float*)d_in[14];
    const float* offy_b  = (const float*)d_in[15];
    const float* gnoffy_g= (const float*)d_in[16];
    const float* gnoffy_b= (const float*)d_in[17];
    const float* dscy_w  = (const float*)d_in[18];
    const float* dscy_b  = (const float*)d_in[19];
    const float* gny_g   = (const float*)d_in[20];
    const float* gny_b   = (const float*)d_in[21];
    const float* conv2_w = (const float*)d_in[22];
    const float* bn2_g   = (const float*)d_in[23];
    const float* bn2_b   = (const float*)d_in[24];
    const float* bn2_m   = (const float*)d_in[25];
    const float* bn2_v   = (const float*)d_in[26];

    float* ws = (float*)d_ws;
    unsigned short* hb = (unsigned short*)ws;   // 8,388,608 bf16 = 4,194,304 floats
    float* offx     = ws + 4194304;             // 1,310,720
    float* offy     = offx + 1310720;           // 1,310,720
    float* cat      = offy + 1310720;           // 2,097,152
    float* raw      = cat + 2097152;            // 40 offset sums
    float* raw2     = raw + 40;                 // 16 cat sums (zeroed as 64 total)

    k_conv1<<<1024, 256, 0, stream>>>(x, conv1_w, bn1_g, bn1_b, bn1_m, bn1_v, hb, raw);
    k_offconv<<<1024, 256, 0, stream>>>(hb, offx_w, offy_w, offx_b, offy_b,
                                        offx, offy, raw);
    k_dsc<<<dim3(512, 2), 256, 0, stream>>>(hb, offx, offy, raw,
                                            gnoffx_g, gnoffx_b, gnoffy_g, gnoffy_b,
                                            dscx_w, dscy_w, dscx_b, dscy_b,
                                            cat, raw2);
    k_final<<<2048, 256, 0, stream>>>(cat, raw2, gnx_g, gnx_b, gny_g, gny_b,
                                      conv2_w, bn2_g, bn2_b, bn2_m, bn2_v,
                                      (float*)d_out);
}

// Round 14
// 317.492 us; speedup vs baseline: 1.0515x; 1.0515x over previous
//
#include <hip/hip_runtime.h>
#include <hip/hip_bf16.h>

// h stored bf16 chunk layout [b][4][65536 px][16c] (entry = 32 B)
// k_pack: one-time pack of offconv weights into MFMA B-fragment layout (global)
// k_offconv: implicit-GEMM MFMA 16x16x32 bf16, batched A-loads, B from hot
//            global bpack (no LDS staging). grid 1024, 2 tiles/wave.
// k_dsc: GN+tanh inline, 2-pt lerp (bf16 h -> fp32) + K=5 conv -> cat
// final: GN + 1x1 conv 16->64 + BN + ReLU -> fp32 NCHW

#define EPSF 1e-5f

typedef __attribute__((ext_vector_type(4))) float f4;
typedef __attribute__((ext_vector_type(8))) short bf8;
typedef __attribute__((ext_vector_type(8))) unsigned short us8;

static __device__ __forceinline__ unsigned pk2(float lo, float hi) {
    unsigned a = __float_as_uint(lo), b = __float_as_uint(hi);
    a = (a + 0x7FFFu + ((a >> 16) & 1)) >> 16;
    b = (b + 0x7FFFu + ((b >> 16) & 1)) >> 16;
    return a | (b << 16);
}
static __device__ __forceinline__ float bu2f(unsigned short u) {
    return __uint_as_float(((unsigned)u) << 16);
}

// ---------------- Kernel 0: pack offconv weights to B-fragment layout ---------
// bpack[e][nt][lane][8] bf16, e = tap*2+kt  (18432 entries, 36 KB)
__global__ __launch_bounds__(256) void k_pack(
    const float* __restrict__ wx, const float* __restrict__ wy,
    unsigned short* __restrict__ bpack)
{
    int idx = blockIdx.x * 256 + threadIdx.x;
    if (idx >= 18432) return;
    int jj = idx & 7;
    int lane_ = (idx >> 3) & 63;
    int nt = (idx >> 9) & 1;
    int kt = (idx >> 10) & 1;
    int tap = idx >> 11;
    int c = kt * 32 + (lane_ >> 4) * 8 + jj;
    int oc = nt * 16 + (lane_ & 15);
    float v = 0.f;
    if (oc < 10) v = wx[((size_t)oc * 64 + c) * 9 + tap];
    else if (oc < 20) v = wy[((size_t)(oc - 10) * 64 + c) * 9 + tap];
    unsigned uu = __float_as_uint(v);
    uu = (uu + 0x7FFFu + ((uu >> 16) & 1)) >> 16;
    bpack[idx] = (unsigned short)uu;
}

// ---------------- Kernel 1: conv1 + bn1 + relu -> h bf16 chunked --------------
__global__ __launch_bounds__(256) void k_conv1(
    const float* __restrict__ x, const float* __restrict__ w,
    const float* __restrict__ g, const float* __restrict__ bb,
    const float* __restrict__ m, const float* __restrict__ v,
    unsigned short* __restrict__ hb, float* __restrict__ statsraw)
{
    __shared__ float wl[27 * 64];            // [tap][oc]
    __shared__ float scale[64], shift[64];
    int t = threadIdx.x;
    if (blockIdx.x == 0 && t < 64) statsraw[t] = 0.f;   // zero raw(40)+raw2(16)
    for (int idx = t; idx < 1728; idx += 256) {
        int tap = idx >> 6, oc = idx & 63;
        wl[idx] = w[oc * 27 + tap];
    }
    if (t < 64) {
        float sc = g[t] * rsqrtf(v[t] + EPSF);
        scale[t] = sc; shift[t] = bb[t] - m[t] * sc;
    }
    __syncthreads();
    int lane = t & 63, wid = t >> 6;
    int blk = blockIdx.x;
    int b = blk >> 9;
    int rem = blk & 511;
    int i0 = (rem >> 2) * 2;
    int j0 = (rem & 3) * 64;
    int j = j0 + lane;
    f4 acc[2][4];
    #pragma unroll
    for (int r = 0; r < 2; ++r)
        #pragma unroll
        for (int q = 0; q < 4; ++q) acc[r][q] = (f4)0.f;
    #pragma unroll
    for (int ic = 0; ic < 3; ++ic) {
        #pragma unroll
        for (int dy = 0; dy < 3; ++dy) {
            const float* rowp[2]; bool vy[2];
            #pragma unroll
            for (int r = 0; r < 2; ++r) {
                int y = 2 * (i0 + r) + dy - 1;
                vy[r] = (unsigned)y < 512u;
                rowp[r] = x + ((size_t)(b * 3 + ic) * 512 + (vy[r] ? y : 0)) * 512;
            }
            #pragma unroll
            for (int dx = 0; dx < 3; ++dx) {
                int xx = 2 * j + dx - 1;
                bool vx = (unsigned)xx < 512u;
                int tap = ic * 9 + dy * 3 + dx;
                f4 w4[4];
                #pragma unroll
                for (int q = 0; q < 4; ++q)
                    w4[q] = *(const f4*)&wl[tap * 64 + wid * 16 + q * 4];
                #pragma unroll
                for (int r = 0; r < 2; ++r) {
                    float xv = (vy[r] && vx) ? rowp[r][xx] : 0.f;
                    #pragma unroll
                    for (int q = 0; q < 4; ++q) acc[r][q] += xv * w4[q];
                }
            }
        }
    }
    #pragma unroll
    for (int r = 0; r < 2; ++r) {
        size_t ij = (size_t)(i0 + r) * 256 + j;
        unsigned* hp = (unsigned*)(hb + ((size_t)(b * 4 + wid) * 65536 + ij) * 16);
        unsigned u[8];
        #pragma unroll
        for (int q = 0; q < 4; ++q) {
            f4 sc = *(const f4*)&scale[wid * 16 + q * 4];
            f4 sh = *(const f4*)&shift[wid * 16 + q * 4];
            f4 val = acc[r][q] * sc + sh;
            float v0 = fmaxf(val[0], 0.f), v1 = fmaxf(val[1], 0.f);
            float v2 = fmaxf(val[2], 0.f), v3 = fmaxf(val[3], 0.f);
            u[q * 2] = pk2(v0, v1);
            u[q * 2 + 1] = pk2(v2, v3);
        }
        *(uint4*)hp = make_uint4(u[0], u[1], u[2], u[3]);
        *(uint4*)(hp + 4) = make_uint4(u[4], u[5], u[6], u[7]);
    }
}

// ---------------- Kernel 2: offset convs via MFMA implicit GEMM ---------------
// grid 1024 x 256 thr (4 waves); wave does 2 tiles of 16 px; N=32.
// A-loads batched; B-fragments loaded from hot global bpack (no LDS staging).
__global__ __launch_bounds__(256) void k_offconv(
    const unsigned short* __restrict__ hb,
    const unsigned short* __restrict__ bpack,
    const float* __restrict__ bx, const float* __restrict__ by,
    float* __restrict__ offx, float* __restrict__ offy,
    float* __restrict__ raw)
{
    __shared__ float wsum[4][2][16][2];
    int t = threadIdx.x;
    int lane = t & 63, wid = t >> 6;
    int m = lane & 15, quad = lane >> 4;
    int blk = blockIdx.x;
    int b = blk >> 9;
    float bias_a = (m < 10) ? bx[m] : by[m - 10];
    bool vb = (m < 4);
    float bias_b = vb ? by[6 + m] : 0.f;
    float s0 = 0.f, q0 = 0.f, s1 = 0.f, q1 = 0.f;
    const unsigned short* hb_b = hb + (size_t)b * 4194304;
    const unsigned short* bl = bpack + lane * 8;
    #pragma unroll 1
    for (int tt = 0; tt < 2; ++tt) {
        int p0 = blk * 128 + wid * 32 + tt * 16;
        int ij = p0 & 65535;
        int i = ij >> 8, j0 = ij & 255;
        // ---- batch all 18 A-fragment loads ----
        bf8 afr[18];
        #pragma unroll
        for (int ky = 0; ky < 3; ++ky) {
            int y = i + ky - 1;
            bool vy = (unsigned)y < 256u;
            int yc = vy ? y : 0;
            #pragma unroll
            for (int kx = 0; kx < 3; ++kx) {
                int xc = j0 + m + kx - 1;
                bool vx = (unsigned)xc < 256u;
                bool ok = vy && vx;
                int pix = yc * 256 + (vx ? xc : 0);
                #pragma unroll
                for (int kt = 0; kt < 2; ++kt) {
                    int chunkk = kt * 2 + (quad >> 1);
                    const unsigned short* ap =
                        hb_b + ((size_t)chunkk * 65536 + pix) * 16 + (quad & 1) * 8;
                    bf8 av = *(const bf8*)ap;
                    afr[(ky * 3 + kx) * 2 + kt] = ok ? av : (bf8)0;
                }
            }
        }
        // ---- MFMA over all 18 K-slices; B from global (L1/L2-hot 36 KB) ----
        f4 acc0 = (f4)0.f, acc1 = (f4)0.f;
        #pragma unroll
        for (int e = 0; e < 18; ++e) {
            bf8 b0 = *(const bf8*)(bl + (size_t)e * 1024);
            bf8 b1 = *(const bf8*)(bl + (size_t)e * 1024 + 512);
            acc0 = __builtin_amdgcn_mfma_f32_16x16x32_bf16(afr[e], b0, acc0, 0, 0, 0);
            acc1 = __builtin_amdgcn_mfma_f32_16x16x32_bf16(afr[e], b1, acc1, 0, 0, 0);
        }
        // ---- epilogue: bias, store, stats partials ----
        #pragma unroll
        for (int r = 0; r < 4; ++r) {
            int p = p0 + quad * 4 + r;
            float v0 = acc0[r] + bias_a;
            s0 += v0; q0 += v0 * v0;
            if (m < 10) offx[(size_t)p * 10 + m] = v0;
            else        offy[(size_t)p * 10 + m - 10] = v0;
            if (vb) {
                float v1 = acc1[r] + bias_b;
                s1 += v1; q1 += v1 * v1;
                offy[(size_t)p * 10 + 6 + m] = v1;
            }
        }
    }
    s0 += __shfl_xor(s0, 16, 64); q0 += __shfl_xor(q0, 16, 64);
    s1 += __shfl_xor(s1, 16, 64); q1 += __shfl_xor(q1, 16, 64);
    s0 += __shfl_xor(s0, 32, 64); q0 += __shfl_xor(q0, 32, 64);
    s1 += __shfl_xor(s1, 32, 64); q1 += __shfl_xor(q1, 32, 64);
    if (quad == 0) {
        wsum[wid][0][m][0] = s0; wsum[wid][0][m][1] = q0;
        wsum[wid][1][m][0] = s1; wsum[wid][1][m][1] = q1;
    }
    __syncthreads();
    if (t < 20) {
        float ss = 0.f, qq = 0.f;
        if (t < 16) {
            #pragma unroll
            for (int w_ = 0; w_ < 4; ++w_) { ss += wsum[w_][0][t][0]; qq += wsum[w_][0][t][1]; }
        } else {
            #pragma unroll
            for (int w_ = 0; w_ < 4; ++w_) { ss += wsum[w_][1][t - 16][0]; qq += wsum[w_][1][t - 16][1]; }
        }
        int oc = t;
        int branch = oc < 10 ? 0 : 1;
        int c = oc - branch * 10;
        int gid = branch * 10 + b * 5 + (c >> 1);
        atomicAdd(&raw[gid * 2], ss);
        atomicAdd(&raw[gid * 2 + 1], qq);
    }
}

// ---------------- Kernel 3: GN+tanh inline + 2pt-lerp (bf16) + deform conv ----
// block = 256; 64 j (lanes) x 4 i (4 waves x 1 row). grid (512,2).
__global__ __launch_bounds__(256) void k_dsc(
    const unsigned short* __restrict__ hb,
    const float* __restrict__ offx, const float* __restrict__ offy,
    const float* __restrict__ raw,
    const float* __restrict__ gx, const float* __restrict__ bxg,
    const float* __restrict__ gy, const float* __restrict__ byg,
    const float* __restrict__ wx_, const float* __restrict__ wy_,
    const float* __restrict__ bx_, const float* __restrict__ by_,
    float* __restrict__ cat,
    float* __restrict__ raw2)
{
    int branch = blockIdx.y;
    __shared__ float wl[2560];               // [k][c][oc8]
    __shared__ float bias[8];
    __shared__ float ws2[4][4];
    const float* wsrc = branch ? wy_ : wx_;
    int t = threadIdx.x;
    for (int idx = t; idx < 2560; idx += 256) {
        int oc = idx & 7;
        int rest = idx >> 3;                 // k*64 + c
        wl[idx] = wsrc[(size_t)oc * 320 + (rest & 63) * 5 + (rest >> 6)];
    }
    if (t < 8) bias[t] = (branch ? by_ : bx_)[t];
    __syncthreads();
    int lane = t & 63, wid = t >> 6;
    int blk = blockIdx.x;
    int b = blk >> 8;
    int rem = blk & 255;
    int i = (rem >> 2) * 4 + wid;
    int j = (rem & 3) * 64 + lane;
    const float* offarr = branch ? offy : offx;
    const float* goff = branch ? gy : gx;
    const float* boff = branch ? byg : bxg;
    int cbase = branch * 5;
    const int idxs[4] = {0, 1, 3, 4};
    float cum[5];
    {
        size_t p = (size_t)b * 65536 + (size_t)i * 256 + j;
        const float* op = offarr + p * 10 + cbase;
        float tv[4];
        #pragma unroll
        for (int u = 0; u < 4; ++u) {
            int c = cbase + idxs[u];
            int g = c >> 1;
            int sidx = branch * 10 + b * 5 + g;
            float ss = raw[sidx * 2], qq = raw[sidx * 2 + 1];
            float mean = ss * (1.f / 131072.f);
            float var = qq * (1.f / 131072.f) - mean * mean;
            float val = (op[idxs[u]] - mean) * rsqrtf(var + EPSF) * goff[c] + boff[c];
            tv[u] = tanhf(val);
        }
        cum[0] = tv[0] + tv[1]; cum[1] = tv[1]; cum[2] = 0.f;
        cum[3] = tv[2]; cum[4] = tv[2] + tv[3];
    }
    f4 acc0 = (f4)0.f, acc1 = (f4)0.f;
    #pragma unroll 1
    for (int k = 0; k < 5; ++k) {
        int pixA, pixB; float fr;
        if (branch == 0) {
            float yf = (float)i + cum[k];
            yf = fminf(fmaxf(yf, 0.f), 255.f);
            float y0 = floorf(yf);
            fr = yf - y0;
            int y0i = (int)y0;
            int y1i = min(y0i + 1, 255);
            int xi = min(max(j + k - 2, 0), 255);
            pixA = y0i * 256 + xi;
            pixB = y1i * 256 + xi;
        } else {
            float xf = (float)j + cum[k];
            xf = fminf(fmaxf(xf, 0.f), 255.f);
            float x0 = floorf(xf);
            fr = xf - x0;
            int x0i = (int)x0;
            int x1i = min(x0i + 1, 255);
            int yi = min(max(i + k - 2, 0), 255);
            pixA = yi * 256 + x0i;
            pixB = yi * 256 + x1i;
        }
        #pragma unroll 1
        for (int chunk = 0; chunk < 4; ++chunk) {
            const unsigned short* hc = hb + ((size_t)(b * 4 + chunk) * 65536) * 16;
            const float* wk = &wl[((size_t)k * 64 + chunk * 16) * 8];
            us8 aLo = *(const us8*)(hc + (size_t)pixA * 16);
            us8 aHi = *(const us8*)(hc + (size_t)pixA * 16 + 8);
            us8 bLo = *(const us8*)(hc + (size_t)pixB * 16);
            us8 bHi = *(const us8*)(hc + (size_t)pixB * 16 + 8);
            #pragma unroll
            for (int cq = 0; cq < 4; ++cq) {
                #pragma unroll
                for (int ci = 0; ci < 4; ++ci) {
                    int e = cq * 4 + ci;
                    float av = (e < 8) ? bu2f(aLo[e & 7]) : bu2f(aHi[e & 7]);
                    float bv = (e < 8) ? bu2f(bLo[e & 7]) : bu2f(bHi[e & 7]);
                    float vf = av + fr * (bv - av);
                    f4 w0 = *(const f4*)&wk[e * 8];
                    f4 w1 = *(const f4*)&wk[e * 8 + 4];
                    acc0 += vf * w0;
                    acc1 += vf * w1;
                }
            }
        }
    }
    float sg0 = 0.f, sq0 = 0.f, sg1 = 0.f, sq1 = 0.f;
    {
        size_t p = (size_t)b * 65536 + (size_t)i * 256 + j;
        f4 v0 = acc0 + *(const f4*)&bias[0];
        f4 v1 = acc1 + *(const f4*)&bias[4];
        *(f4*)&cat[p * 16 + branch * 8] = v0;
        *(f4*)&cat[p * 16 + branch * 8 + 4] = v1;
        #pragma unroll
        for (int e = 0; e < 4; ++e) {
            sg0 += v0[e]; sq0 += v0[e] * v0[e];
            sg1 += v1[e]; sq1 += v1[e] * v1[e];
        }
    }
    #pragma unroll
    for (int d = 32; d >= 1; d >>= 1) {
        sg0 += __shfl_xor(sg0, d, 64); sq0 += __shfl_xor(sq0, d, 64);
        sg1 += __shfl_xor(sg1, d, 64); sq1 += __shfl_xor(sq1, d, 64);
    }
    if (lane == 0) {
        ws2[wid][0] = sg0; ws2[wid][1] = sq0; ws2[wid][2] = sg1; ws2[wid][3] = sq1;
    }
    __syncthreads();
    if (t < 4) {
        float val = ws2[0][t] + ws2[1][t] + ws2[2][t] + ws2[3][t];
        int g0 = b * 4 + branch * 2;
        int gi = g0 + (t >> 1);
        atomicAdd(&raw2[gi * 2 + (t & 1)], val);
    }
}

// ---------------- Kernel 4: GN+relu + 1x1 conv + bn2 + relu -> fp32 out -------
__global__ __launch_bounds__(256) void k_final(
    const float* __restrict__ cat,
    const float* __restrict__ raw2,
    const float* __restrict__ gnx_g, const float* __restrict__ gnx_b,
    const float* __restrict__ gny_g, const float* __restrict__ gny_b,
    const float* __restrict__ w2,
    const float* __restrict__ g2, const float* __restrict__ b2,
    const float* __restrict__ m2, const float* __restrict__ v2,
    float* __restrict__ out)
{
    __shared__ float wl[1024];
    __shared__ float sc2[64], sh2[64];
    __shared__ float cmean[16], crstd[16], cg[16], cb[16];
    int t = threadIdx.x;
    int pbase = blockIdx.x * 64;
    int b = pbase >> 16;
    for (int idx = t; idx < 1024; idx += 256) wl[idx] = w2[idx];
    if (t < 64) {
        float sc = g2[t] * rsqrtf(v2[t] + EPSF);
        sc2[t] = sc;
        sh2[t] = b2[t] - m2[t] * sc;
    }
    if (t < 16) {
        int branch = t >> 3; int cc = t & 7; int g = cc >> 2;
        int sidx = b * 4 + branch * 2 + g;
        float ss = raw2[sidx * 2], qq = raw2[sidx * 2 + 1];
        float mean = ss * (1.f / 262144.f);
        float var = qq * (1.f / 262144.f) - mean * mean;
        cmean[t] = mean;
        crstd[t] = rsqrtf(var + EPSF);
        cg[t] = branch ? gny_g[cc] : gnx_g[cc];
        cb[t] = branch ? gny_b[cc] : gnx_b[cc];
    }
    __syncthreads();
    int lane = t & 63, wq = t >> 6;
    int p = pbase + lane;
    int ij = p & 65535;
    float vv[16];
    const float* cp = &cat[(size_t)p * 16];
    #pragma unroll
    for (int c = 0; c < 16; ++c) {
        float x = (cp[c] - cmean[c]) * crstd[c] * cg[c] + cb[c];
        vv[c] = fmaxf(x, 0.f);
    }
    #pragma unroll
    for (int q = 0; q < 16; ++q) {
        int oc = wq + q * 4;
        float s = 0.f;
        #pragma unroll
        for (int c = 0; c < 16; ++c) s += vv[c] * wl[oc * 16 + c];
        float r = fmaxf(s * sc2[oc] + sh2[oc], 0.f);
        out[((size_t)(b * 64 + oc) << 16) + ij] = r;
    }
}

extern "C" void kernel_launch(void* const* d_in, const int* in_sizes, int n_in,
                              void* d_out, int out_size, void* d_ws, size_t ws_size,
                              hipStream_t stream) {
    const float* x       = (const float*)d_in[0];
    const float* conv1_w = (const float*)d_in[1];
    const float* bn1_g   = (const float*)d_in[2];
    const float* bn1_b   = (const float*)d_in[3];
    const float* bn1_m   = (const float*)d_in[4];
    const float* bn1_v   = (const float*)d_in[5];
    const float* offx_w  = (const float*)d_in[6];
    const float* offx_b  = (const float*)d_in[7];
    const float* gnoffx_g= (const float*)d_in[8];
    const float* gnoffx_b= (const float*)d_in[9];
    const float* dscx_w  = (const float*)d_in[10];
    const float* dscx_b  = (const float*)d_in[11];
    const float* gnx_g   = (const float*)d_in[12];
    const float* gnx_b   = (const float*)d_in[13];
    const float* offy_w  = (const float*)d_in[14];
    const float* offy_b  = (const float*)d_in[15];
    const float* gnoffy_g= (const float*)d_in[16];
    const float* gnoffy_b= (const float*)d_in[17];
    const float* dscy_w  = (const float*)d_in[18];
    const float* dscy_b  = (const float*)d_in[19];
    const float* gny_g   = (const float*)d_in[20];
    const float* gny_b   = (const float*)d_in[21];
    const float* conv2_w = (const float*)d_in[22];
    const float* bn2_g   = (const float*)d_in[23];
    const float* bn2_b   = (const float*)d_in[24];
    const float* bn2_m   = (const float*)d_in[25];
    const float* bn2_v   = (const float*)d_in[26];

    float* ws = (float*)d_ws;
    unsigned short* hb = (unsigned short*)ws;   // 8,388,608 bf16 = 4,194,304 floats
    float* offx     = ws + 4194304;             // 1,310,720
    float* offy     = offx + 1310720;           // 1,310,720
    float* cat      = offy + 1310720;           // 2,097,152
    float* raw      = cat + 2097152;            // 40 offset sums
    float* raw2     = raw + 40;                 // 16 cat sums (zeroed as 64 total)
    unsigned short* bpack = (unsigned short*)(raw2 + 24);  // 18432 bf16 = 9216 floats

    k_pack<<<72, 256, 0, stream>>>(offx_w, offy_w, bpack);
    k_conv1<<<1024, 256, 0, stream>>>(x, conv1_w, bn1_g, bn1_b, bn1_m, bn1_v, hb, raw);
    k_offconv<<<1024, 256, 0, stream>>>(hb, bpack, offx_b, offy_b,
                                        offx, offy, raw);
    k_dsc<<<dim3(512, 2), 256, 0, stream>>>(hb, offx, offy, raw,
                                            gnoffx_g, gnoffx_b, gnoffy_g, gnoffy_b,
                                            dscx_w, dscy_w, dscx_b, dscy_b,
                                            cat, raw2);
    k_final<<<2048, 256, 0, stream>>>(cat, raw2, gnx_g, gnx_b, gny_g, gny_b,
                                      conv2_w, bn2_g, bn2_b, bn2_m, bn2_v,
                                      (float*)d_out);
}